// Round 1
// baseline (201157.751 us; speedup 1.0000x reference)
//
#include <hip/hip_runtime.h>
#include <hip/hip_bf16.h>
#include <math.h>

#define B 8
#define T 1024
#define D 1024
#define H 16
#define DH 64
#define NSTEPS 4

__device__ __forceinline__ float sigmoidf_(float x) { return 1.0f / (1.0f + expf(-x)); }

// ---------------------------------------------------------------------------
// Generic tiled fp32 GEMM: C[M,N] = A[M,K] @ W[N,K]^T + bias[N]
// W row n element k at W[n*ldw + koff + k].
// MODE 0: C[m*N + n]
// MODE 1: qkv scatter: n -> which=n>>10 (q/k/v), h=(n&1023)>>6, dh=n&63;
//         m -> b=m>>10, t=m&1023; dst[((b*H+h)*T + t)*DH + dh]
// ---------------------------------------------------------------------------
template <int MODE>
__global__ __launch_bounds__(256) void gemm_kernel(
    const float* __restrict__ A, const float* __restrict__ W,
    const float* __restrict__ bias, float* __restrict__ C,
    int M, int N, int K, int ldw, int koff,
    float* __restrict__ qb, float* __restrict__ kb, float* __restrict__ vb)
{
    __shared__ float As[32][68];
    __shared__ float Ws[32][68];
    const int m0 = blockIdx.x * 64, n0 = blockIdx.y * 64;
    const int tid = threadIdx.x;
    const int tn = tid & 15, tm = tid >> 4;
    float acc[4][4] = {};

    for (int k0 = 0; k0 < K; k0 += 32) {
#pragma unroll
        for (int j = 0; j < 2; ++j) {
            int lin = tid + j * 256;       // 0..511
            int r = lin >> 3, c4 = lin & 7;
            float4 av = *(const float4*)(A + (size_t)(m0 + r) * K + k0 + c4 * 4);
            As[c4 * 4 + 0][r] = av.x; As[c4 * 4 + 1][r] = av.y;
            As[c4 * 4 + 2][r] = av.z; As[c4 * 4 + 3][r] = av.w;
            float4 wv = *(const float4*)(W + (size_t)(n0 + r) * ldw + koff + k0 + c4 * 4);
            Ws[c4 * 4 + 0][r] = wv.x; Ws[c4 * 4 + 1][r] = wv.y;
            Ws[c4 * 4 + 2][r] = wv.z; Ws[c4 * 4 + 3][r] = wv.w;
        }
        __syncthreads();
#pragma unroll
        for (int k = 0; k < 32; ++k) {
            float a_[4], b_[4];
            *(float4*)a_ = *(const float4*)&As[k][tm * 4];
            *(float4*)b_ = *(const float4*)&Ws[k][tn * 4];
#pragma unroll
            for (int i = 0; i < 4; ++i)
#pragma unroll
                for (int j = 0; j < 4; ++j) acc[i][j] += a_[i] * b_[j];
        }
        __syncthreads();
    }

#pragma unroll
    for (int i = 0; i < 4; ++i) {
        int m = m0 + tm * 4 + i;
#pragma unroll
        for (int j = 0; j < 4; ++j) {
            int n = n0 + tn * 4 + j;
            float v = acc[i][j] + bias[n];
            if (MODE == 0) {
                C[(size_t)m * N + n] = v;
            } else {
                int which = n >> 10;
                int hh = (n & 1023) >> 6;
                int dh = n & 63;
                int b = m >> 10, t = m & 1023;
                float* dst = (which == 0) ? qb : ((which == 1) ? kb : vb);
                dst[(((size_t)(b * H + hh)) * T + t) * DH + dh] = v;
            }
        }
    }
}

// ---------------------------------------------------------------------------
// Flash attention fp32. q/k/v layout: [B*H, T, DH]. Writes ctx [B,T,D].
// Block: one (b,h) pair + one 64-row q block. 256 threads:
//   row = tid&63 (q row), seg = tid>>6 (16-col segment of kj / output cols)
// ---------------------------------------------------------------------------
__global__ __launch_bounds__(256) void attn_kernel(
    const float* __restrict__ qb, const float* __restrict__ kb,
    const float* __restrict__ vb, float* __restrict__ ctx)
{
    __shared__ float Qs[64][65];
    __shared__ float Ks[64][65];   // reused to hold P after S is consumed
    __shared__ float Vs[64][65];
    __shared__ float mrow[64], lrow[64], srow[64];
    __shared__ float tred[64][4];

    const int tid = threadIdx.x;
    const int row = tid & 63, seg = tid >> 6;
    const int bx = blockIdx.x;
    const int qblk = bx & 15;
    const int bh = bx >> 4;                 // b*16 + h
    const float* qp = qb + (size_t)bh * T * DH;
    const float* kp = kb + (size_t)bh * T * DH;
    const float* vp = vb + (size_t)bh * T * DH;

    // load Q block
#pragma unroll
    for (int i = 0; i < 4; ++i) {
        int lin = tid + i * 256;            // 0..1023
        int r = lin >> 4, c4 = lin & 15;
        float4 v = *(const float4*)(qp + (size_t)(qblk * 64 + r) * DH + c4 * 4);
        Qs[r][c4 * 4 + 0] = v.x; Qs[r][c4 * 4 + 1] = v.y;
        Qs[r][c4 * 4 + 2] = v.z; Qs[r][c4 * 4 + 3] = v.w;
    }
    if (tid < 64) { mrow[tid] = -3.0e38f; lrow[tid] = 0.0f; }

    float Oacc[16];
#pragma unroll
    for (int j = 0; j < 16; ++j) Oacc[j] = 0.0f;

    for (int kt = 0; kt < 16; ++kt) {
        __syncthreads();                    // prev PV done; P-in-Ks consumed
#pragma unroll
        for (int i = 0; i < 4; ++i) {
            int lin = tid + i * 256;
            int r = lin >> 4, c4 = lin & 15;
            float4 kv = *(const float4*)(kp + (size_t)(kt * 64 + r) * DH + c4 * 4);
            Ks[r][c4 * 4 + 0] = kv.x; Ks[r][c4 * 4 + 1] = kv.y;
            Ks[r][c4 * 4 + 2] = kv.z; Ks[r][c4 * 4 + 3] = kv.w;
            float4 vv = *(const float4*)(vp + (size_t)(kt * 64 + r) * DH + c4 * 4);
            Vs[r][c4 * 4 + 0] = vv.x; Vs[r][c4 * 4 + 1] = vv.y;
            Vs[r][c4 * 4 + 2] = vv.z; Vs[r][c4 * 4 + 3] = vv.w;
        }
        __syncthreads();

        // S = Q K^T / 8 for this thread's 16 kj
        float sacc[16];
#pragma unroll
        for (int j = 0; j < 16; ++j) sacc[j] = 0.0f;
        for (int k = 0; k < 64; ++k) {
            float qv = Qs[row][k];
#pragma unroll
            for (int j = 0; j < 16; ++j) sacc[j] += qv * Ks[seg * 16 + j][k];
        }
        float tmax = -3.0e38f;
#pragma unroll
        for (int j = 0; j < 16; ++j) { sacc[j] *= 0.125f; tmax = fmaxf(tmax, sacc[j]); }
        tred[row][seg] = tmax;
        __syncthreads();                    // also: everyone done reading Ks
        if (seg == 0) {
            float mt = fmaxf(fmaxf(tred[row][0], tred[row][1]),
                             fmaxf(tred[row][2], tred[row][3]));
            float mo = mrow[row];
            float mn = fmaxf(mo, mt);
            srow[row] = expf(mo - mn);
            mrow[row] = mn;
        }
        __syncthreads();
        float mn = mrow[row], sc = srow[row];
        float psum = 0.0f;
#pragma unroll
        for (int j = 0; j < 16; ++j) {
            float p = expf(sacc[j] - mn);
            Ks[row][seg * 16 + j] = p;      // P stored into Ks
            psum += p;
        }
        tred[row][seg] = psum;
#pragma unroll
        for (int j = 0; j < 16; ++j) Oacc[j] *= sc;
        __syncthreads();
        if (seg == 0)
            lrow[row] = lrow[row] * sc +
                        (tred[row][0] + tred[row][1] + tred[row][2] + tred[row][3]);
        // PV
        for (int kj = 0; kj < 64; ++kj) {
            float pv = Ks[row][kj];
#pragma unroll
            for (int j = 0; j < 16; ++j) Oacc[j] += pv * Vs[kj][seg * 16 + j];
        }
    }
    __syncthreads();
    float linv = 1.0f / lrow[row];
    int b = bh >> 4, hh = bh & 15;
    int q = qblk * 64 + row;
#pragma unroll
    for (int j = 0; j < 16; ++j)
        ctx[((size_t)(b * T + q)) * D + hh * 64 + seg * 16 + j] = Oacc[j] * linv;
}

// ---------------------------------------------------------------------------
// GRU phase A: h' = GRUCell(tok, h) given precomputed gi.
// grid 128 blocks x 256 thr. Thread: dl=tid>>5, b=(tid&31)>>2, kp=tid&3.
// ---------------------------------------------------------------------------
__global__ __launch_bounds__(256) void gru_kernelA(
    const float* __restrict__ h, float* __restrict__ hp,
    const float* __restrict__ w_hh, const float* __restrict__ b_hh,
    const float* __restrict__ gi, int t)
{
    __shared__ float red[8][8][4][3];
    const int tid = threadIdx.x;
    const int dl = tid >> 5, sub = tid & 31, b = sub >> 2, kp = sub & 3;
    const int dg = blockIdx.x * 8 + dl;
    const float* hrow = h + b * D + kp * 256;
    const float* wr = w_hh + (size_t)dg * D + kp * 256;
    const float* wz = w_hh + (size_t)(D + dg) * D + kp * 256;
    const float* wn = w_hh + (size_t)(2 * D + dg) * D + kp * 256;
    float ar = 0.0f, az = 0.0f, an = 0.0f;
    for (int k = 0; k < 256; k += 4) {
        float4 hv = *(const float4*)(hrow + k);
        float4 wrv = *(const float4*)(wr + k);
        float4 wzv = *(const float4*)(wz + k);
        float4 wnv = *(const float4*)(wn + k);
        ar += hv.x * wrv.x + hv.y * wrv.y + hv.z * wrv.z + hv.w * wrv.w;
        az += hv.x * wzv.x + hv.y * wzv.y + hv.z * wzv.z + hv.w * wzv.w;
        an += hv.x * wnv.x + hv.y * wnv.y + hv.z * wnv.z + hv.w * wnv.w;
    }
    red[dl][b][kp][0] = ar; red[dl][b][kp][1] = az; red[dl][b][kp][2] = an;
    __syncthreads();
    if (tid < 64) {
        int dl2 = tid >> 3, b2 = tid & 7;
        int dg2 = blockIdx.x * 8 + dl2;
        float gr = 0.0f, gz = 0.0f, gn = 0.0f;
#pragma unroll
        for (int q = 0; q < 4; ++q) {
            gr += red[dl2][b2][q][0];
            gz += red[dl2][b2][q][1];
            gn += red[dl2][b2][q][2];
        }
        gr += b_hh[dg2]; gz += b_hh[D + dg2]; gn += b_hh[2 * D + dg2];
        const float* gib = gi + ((size_t)b2 * T + t) * (3 * D);
        float r = sigmoidf_(gib[dg2] + gr);
        float z = sigmoidf_(gib[D + dg2] + gz);
        float n = tanhf(gib[2 * D + dg2] + r * gn);
        float ho = h[b2 * D + dg2];
        hp[b2 * D + dg2] = (1.0f - z) * n + z * ho;
    }
}

// ---------------------------------------------------------------------------
// GRU phase B: g = sigmoid(h' @ gate_w[:, :D]^T + ga[t]); h = g*h' + (1-g)*a
// ---------------------------------------------------------------------------
__global__ __launch_bounds__(256) void gru_kernelB(
    const float* __restrict__ hp, float* __restrict__ h,
    const float* __restrict__ gate_w, const float* __restrict__ ga,
    const float* __restrict__ attn, float* __restrict__ out,
    int t, int last)
{
    __shared__ float red[8][8][4];
    const int tid = threadIdx.x;
    const int dl = tid >> 5, sub = tid & 31, b = sub >> 2, kp = sub & 3;
    const int dg = blockIdx.x * 8 + dl;
    const float* hrow = hp + b * D + kp * 256;
    const float* wg = gate_w + (size_t)dg * (2 * D) + kp * 256;  // cols 0..D-1
    float ag = 0.0f;
    for (int k = 0; k < 256; k += 4) {
        float4 hv = *(const float4*)(hrow + k);
        float4 wv = *(const float4*)(wg + k);
        ag += hv.x * wv.x + hv.y * wv.y + hv.z * wv.z + hv.w * wv.w;
    }
    red[dl][b][kp] = ag;
    __syncthreads();
    if (tid < 64) {
        int dl2 = tid >> 3, b2 = tid & 7;
        int dg2 = blockIdx.x * 8 + dl2;
        float s = red[dl2][b2][0] + red[dl2][b2][1] + red[dl2][b2][2] + red[dl2][b2][3];
        float gav = ga[((size_t)b2 * T + t) * D + dg2];
        float g = sigmoidf_(s + gav);
        float hpv = hp[b2 * D + dg2];
        float av = attn[((size_t)b2 * T + t) * D + dg2];
        float hn = g * hpv + (1.0f - g) * av;
        h[b2 * D + dg2] = hn;
        if (last) out[((size_t)b2 * T + t) * D + dg2] = hn;
    }
}

// ---------------------------------------------------------------------------
extern "C" void kernel_launch(void* const* d_in, const int* in_sizes, int n_in,
                              void* d_out, int out_size, void* d_ws, size_t ws_size,
                              hipStream_t stream)
{
    const float* x          = (const float*)d_in[0];
    const float* in_proj_w  = (const float*)d_in[1];
    const float* in_proj_b  = (const float*)d_in[2];
    const float* out_proj_w = (const float*)d_in[3];
    const float* out_proj_b = (const float*)d_in[4];
    const float* w_ih       = (const float*)d_in[5];
    const float* w_hh       = (const float*)d_in[6];
    const float* b_ih       = (const float*)d_in[7];
    const float* b_hh       = (const float*)d_in[8];
    const float* gate_w     = (const float*)d_in[9];
    const float* gate_b     = (const float*)d_in[10];
    float* out = (float*)d_out;

    float* ws = (float*)d_ws;
    const size_t S1 = (size_t)B * H * T * DH;   // 8,388,608 floats
    float* qb   = ws;
    float* kb   = ws + S1;
    float* vb   = ws + 2 * S1;
    float* ctx  = ws + 3 * S1;
    float* attn = ws + 4 * S1;
    float* ga   = ws + 5 * S1;
    float* gi   = ws;                           // overlaps q/k/v (3*S1 = B*T*3D)
    float* hbuf  = ws + 6 * S1;
    float* hpbuf = hbuf + B * D;

    dim3 blk(256);

    // 1. qkv = x @ in_proj_w^T + b  -> scattered to q/k/v [B*H, T, DH]
    gemm_kernel<1><<<dim3(128, 48), blk, 0, stream>>>(
        x, in_proj_w, in_proj_b, nullptr, B * T, 3 * D, D, D, 0, qb, kb, vb);
    // 2. attention -> ctx [B,T,D]
    attn_kernel<<<dim3(2048), blk, 0, stream>>>(qb, kb, vb, ctx);
    // 3. attn_out = ctx @ out_proj_w^T + b -> attn
    gemm_kernel<0><<<dim3(128, 16), blk, 0, stream>>>(
        ctx, out_proj_w, out_proj_b, attn, B * T, D, D, D, 0,
        nullptr, nullptr, nullptr);
    // 4. ga = attn @ gate_w[:, D:]^T + gate_b
    gemm_kernel<0><<<dim3(128, 16), blk, 0, stream>>>(
        attn, gate_w, gate_b, ga, B * T, D, D, 2 * D, D,
        nullptr, nullptr, nullptr);
    // 5. gi = x @ w_ih^T + b_ih (q/k/v no longer needed)
    gemm_kernel<0><<<dim3(128, 48), blk, 0, stream>>>(
        x, w_ih, b_ih, gi, B * T, 3 * D, D, D, 0,
        nullptr, nullptr, nullptr);

    hipMemsetAsync(hbuf, 0, (size_t)B * D * sizeof(float), stream);

    for (int t = 0; t < T; ++t) {
        for (int s = 0; s < NSTEPS; ++s) {
            gru_kernelA<<<dim3(128), blk, 0, stream>>>(hbuf, hpbuf, w_hh, b_hh, gi, t);
            gru_kernelB<<<dim3(128), blk, 0, stream>>>(hpbuf, hbuf, gate_w, ga, attn,
                                                       out, t, s == NSTEPS - 1);
        }
    }
}